// Round 8
// baseline (104.094 us; speedup 1.0000x reference)
//
#include <hip/hip_runtime.h>
#include <hip/hip_fp16.h>
#include <math.h>
#include <stdint.h>

#define U 50
#define TT 100
#define BB 256
#define BTILE 16
#define NBLK (BB / BTILE)   // 16 blocks

typedef _Float16 f16x8 __attribute__((ext_vector_type(8)));
typedef float f32x4 __attribute__((ext_vector_type(4)));

__device__ __forceinline__ float sigmoid_fast(float x) {
    return 1.0f / (1.0f + __expf(-x));   // saturates cleanly, no NaN
}
__device__ __forceinline__ float tanh_fast(float x) {
    float e = __expf(2.0f * x);
    return 1.0f - 2.0f / (e + 1.0f);     // saturates cleanly, no NaN
}
__device__ __forceinline__ float param_act(float x, float mn, float mx) {
    float scale = 0.5f * (mx - mn);
    return tanh_fast(x) * scale + mn + scale;
}

// f16 index into one h-buffer (16 batches x 64 cols). 16B chunks are
// XOR-swizzled by batch so the A-fragment ds_read_b128 (lanes 0..15 all
// reading different batches at the same chunk) spreads across banks.
__device__ __forceinline__ int swz_idx(int b, int col) {
    return b * 64 + ((((col >> 3) ^ (b & 7)) << 3) | (col & 7));
}

// 16 batches/block, 4 waves. Recurrence as MFMA GEMM:
//   z(16x256) = [h | x | 0](16x64) @ [rec ; kernel ; 0](64x256) + bias
// Wave w owns gate w? No: wave w owns unit-subtile w of ALL 4 gates
// (tiles {w, 4+w, 8+w, 12+w}), so each lane holds all 4 gate z-values for
// its unit and the c/h update is lane-local. B-frags: 32 VGPRs/lane, pinned.
__global__ __launch_bounds__(256, 1) void encoder_kernel(
    const float* __restrict__ x,        // (B,T,4)
    const float* __restrict__ state,    // (B,T,4)
    const float* __restrict__ kernel,   // (4,200)
    const float* __restrict__ rec,      // (50,200)
    const float* __restrict__ bias,     // (200,)
    const float* __restrict__ w_dv, const float* __restrict__ b_dv,
    const float* __restrict__ w_dt, const float* __restrict__ b_dt,
    const float* __restrict__ w_mj, const float* __restrict__ b_mj,
    const float* __restrict__ w_ma, const float* __restrict__ b_ma,
    const float* __restrict__ w_mi, const float* __restrict__ b_mi,
    float* __restrict__ out)            // act_seq (B*T) then idm (B*5)
{
    const int tid = threadIdx.x;
    const int w  = tid >> 6;        // wave 0..3
    const int l  = tid & 63;        // lane
    const int lb = l & 15;          // col-in-tile / batch-in-A
    const int lq = l >> 4;          // quad 0..3
    const int u_lane = w * 16 + lb; // unit owned by this lane (>=U: pad)
    const int bg0 = blockIdx.x * BTILE;

    __shared__ _Float16 hbuf[2][16 * 64];   // double-buffered h~ tile (4 KiB)
    __shared__ float idm_sm[BTILE][5];

    // ---- B fragments (one-time): bf[gate][kstep], 8 f16 each ----
    // B layout: lane holds col n = tile*16 + lb, k = lq*8 + kstep*32 + e
    f16x8 bf[4][2];
    #pragma unroll
    for (int g = 0; g < 4; ++g) {
        #pragma unroll
        for (int ks = 0; ks < 2; ++ks) {
            f16x8 f;
            #pragma unroll
            for (int e = 0; e < 8; ++e) {
                int k = lq * 8 + ks * 32 + e;
                float v = 0.0f;
                if (u_lane < U) {
                    if (k < U)          v = rec[k * 200 + g * U + u_lane];
                    else if (k < U + 4) v = kernel[(k - U) * 200 + g * U + u_lane];
                }
                f[e] = (_Float16)v;
            }
            bf[g][ks] = f;
        }
    }
    // pin (round-4 lesson): asm output can't be rematerialized from global
    #pragma unroll
    for (int g = 0; g < 4; ++g) {
        asm volatile("" : "+v"(bf[g][0]));
        asm volatile("" : "+v"(bf[g][1]));
    }

    float bz[4];
    #pragma unroll
    for (int g = 0; g < 4; ++g)
        bz[g] = (u_lane < U) ? bias[g * U + u_lane] : 0.0f;

    // ---- zero both buffers, stage x(0) ----
    ((uint4*)hbuf)[tid] = uint4{0, 0, 0, 0};   // 256*16B = 4096B = both bufs
    __syncthreads();

    float x_next = 0.0f;
    if (w == 0) {
        const float* xp = x + (size_t)(bg0 + lb) * TT * 4 + lq;
        hbuf[0][swz_idx(lb, U + lq)] = (_Float16)xp[0];   // x(0)
        x_next = xp[4];                                    // x(1)
    }

    float cc[4] = {0.f, 0.f, 0.f, 0.f};

    for (int t = 0; t < TT; ++t) {
        const int cb = t & 1, nb = cb ^ 1;
        __syncthreads();   // h~(t) fully written

        // A fragments: lane holds batch row lb, k = lq*8..+8 (+32)
        const uint4* hb = (const uint4*)&hbuf[cb][0];   // 8 chunks per row
        const int s = lb & 7;
        uint4 a0u = hb[lb * 8 + (lq ^ s)];
        uint4 a1u = hb[lb * 8 + ((lq + 4) ^ s)];
        f16x8 a0 = __builtin_bit_cast(f16x8, a0u);
        f16x8 a1 = __builtin_bit_cast(f16x8, a1u);

        // prefetch x(t+2) under the MFMA/gate phase
        float x_pf = x_next;
        if (w == 0) {
            int tpf = (t + 2 < TT) ? (t + 2) : (TT - 1);
            x_pf = x[((size_t)(bg0 + lb) * TT + tpf) * 4 + lq];
        }

        // z = h~ @ W~ + bias : 2 chained MFMA per gate-tile, 4 tiles
        f32x4 z[4];
        #pragma unroll
        for (int g = 0; g < 4; ++g) {
            f32x4 a;
            a[0] = bz[g]; a[1] = bz[g]; a[2] = bz[g]; a[3] = bz[g];
            a = __builtin_amdgcn_mfma_f32_16x16x32_f16(a0, bf[g][0], a, 0, 0, 0);
            a = __builtin_amdgcn_mfma_f32_16x16x32_f16(a1, bf[g][1], a, 0, 0, 0);
            z[g] = a;
        }

        // gate math: lane's 4 batch rows are lq*4 + r
        #pragma unroll
        for (int r = 0; r < 4; ++r) {
            float ig = sigmoid_fast(z[0][r]);
            float fg = sigmoid_fast(z[1][r]);
            float gg = tanh_fast(z[2][r]);
            float og = sigmoid_fast(z[3][r]);
            float cn = fmaf(fg, cc[r], ig * gg);
            cc[r] = cn;
            float hn = og * tanh_fast(cn);
            if (u_lane < U)
                hbuf[nb][swz_idx(lq * 4 + r, u_lane)] = (_Float16)hn;
        }
        if (w == 0) {
            hbuf[nb][swz_idx(lb, U + lq)] = (_Float16)x_next;  // x(t+1)
            x_next = x_pf;
        }
        // writes go to buf nb; buf cb reads all happened before next barrier
    }
    __syncthreads();   // h(100) complete in hbuf[0]

    // ---- 5 heads x 16 batches on threads 0..79 ----
    if (tid < 80) {
        const int head = tid >> 4;
        const int b = tid & 15;
        const float* wv = (head == 0) ? w_dv : (head == 1) ? w_dt :
                          (head == 2) ? w_mj : (head == 3) ? w_ma : w_mi;
        const float* bv = (head == 0) ? b_dv : (head == 1) ? b_dt :
                          (head == 2) ? b_mj : (head == 3) ? b_ma : b_mi;
        float sum = bv[0];
        #pragma unroll
        for (int u2 = 0; u2 < U; ++u2)
            sum = fmaf((float)hbuf[0][swz_idx(b, u2)], wv[u2], sum);
        float v;
        if (head == 0)      v = param_act(sum, 15.0f, 35.0f);
        else if (head == 1) v = param_act(sum, 0.5f, 3.0f);
        else if (head == 2) v = fmaxf(sum, 0.0f);
        else if (head == 3) v = param_act(sum, 0.5f, 3.0f);
        else                v = param_act(sum, 0.5f, 4.0f);
        idm_sm[b][head] = v;
        out[BB * TT + (bg0 + b) * 5 + head] = v;
    }
    __syncthreads();

    // ---- IDM physics: thread (b = tid>>4, t0 = tid&15) strides T ----
    {
        const int b = tid >> 4;
        const int t0 = tid & 15;
        const int bg = bg0 + b;
        const float desired_v    = idm_sm[b][0];
        const float desired_tgap = idm_sm[b][1];
        const float min_jamx     = idm_sm[b][2];
        const float max_act      = idm_sm[b][3];
        const float min_act      = idm_sm[b][4];
        const float inv_tsab = 1.0f / (2.0f * sqrtf(max_act * min_act));
        const float inv_dv   = 1.0f / desired_v;
        const float4* sb4 = (const float4*)(state + (size_t)bg * TT * 4);
        for (int t = t0; t < TT; t += 16) {
            float4 s4 = sb4[t];
            float vel = s4.x, dv = s4.z, dx = s4.w;
            float dgap = fmaf(desired_tgap, vel, fmaf(vel * dv, inv_tsab, min_jamx));
            float r1 = vel * inv_dv;
            r1 = r1 * r1; r1 = r1 * r1;   // ^4
            float r2 = dgap / dx;
            r2 = r2 * r2;                 // ^2
            out[bg * TT + t] = max_act * (1.0f - (r1 + r2));
        }
    }
}

extern "C" void kernel_launch(void* const* d_in, const int* in_sizes, int n_in,
                              void* d_out, int out_size, void* d_ws, size_t ws_size,
                              hipStream_t stream) {
    const float* x      = (const float*)d_in[0];
    const float* state  = (const float*)d_in[1];
    const float* kern   = (const float*)d_in[2];
    const float* rec    = (const float*)d_in[3];
    const float* bias   = (const float*)d_in[4];
    const float* w_dv   = (const float*)d_in[5];
    const float* b_dv   = (const float*)d_in[6];
    const float* w_dt   = (const float*)d_in[7];
    const float* b_dt   = (const float*)d_in[8];
    const float* w_mj   = (const float*)d_in[9];
    const float* b_mj   = (const float*)d_in[10];
    const float* w_ma   = (const float*)d_in[11];
    const float* b_ma   = (const float*)d_in[12];
    const float* w_mi   = (const float*)d_in[13];
    const float* b_mi   = (const float*)d_in[14];
    float* out = (float*)d_out;

    encoder_kernel<<<NBLK, 256, 0, stream>>>(
        x, state, kern, rec, bias,
        w_dv, b_dv, w_dt, b_dt, w_mj, b_mj, w_ma, b_ma, w_mi, b_mi,
        out);
}

// Round 9
// 87.556 us; speedup vs baseline: 1.1889x; 1.1889x over previous
//
#include <hip/hip_runtime.h>
#include <hip/hip_fp16.h>
#include <math.h>
#include <stdint.h>

#define U 50
#define TT 100
#define BB 256

typedef _Float16 half2v __attribute__((ext_vector_type(2)));

__device__ __forceinline__ void dot2_asm(float& acc, uint32_t h2, uint32_t w2) {
    asm("v_dot2_f32_f16 %0, %1, %2, %0" : "+v"(acc) : "v"(h2), "v"(w2));
}

// Explicit AGPR residency: the allocator cannot rematerialize or spill these
// (opaque asm defs in the "a" register class). Read-back is a 1-VALU move.
#define AWRITE(dst, src) asm volatile("v_accvgpr_write_b32 %0, %1" : "=a"(dst) : "v"(src))
#define AREAD(dst, src)  asm("v_accvgpr_read_b32 %0, %1" : "=v"(dst) : "a"(src))

__device__ __forceinline__ float sigmoid_fast(float x) {
    return 1.0f / (1.0f + __expf(-x));   // saturates cleanly, no NaN
}
__device__ __forceinline__ float tanh_fast(float x) {
    float e = __expf(2.0f * x);
    return 1.0f - 2.0f / (e + 1.0f);     // saturates cleanly, no NaN
}
__device__ __forceinline__ float param_act(float x, float mn, float mx) {
    float scale = 0.5f * (mx - mn);
    return tanh_fast(x) * scale + mn + scale;
}

// One wave per batch element; lane l (<50) owns LSTM unit l. The four gate
// columns of rec (100 packed f16 pairs) + kernel (16) + bias (4) live in
// AGPRs, staged once; per step each value is pulled with v_accvgpr_read and
// consumed by v_dot2_f32_f16. Loop has no global/scratch traffic except the
// pipelined x prefetch. h is exchanged via LDS broadcast; single wave -> no
// barriers.
__global__ __launch_bounds__(64, 1) void encoder_kernel(
    const float* __restrict__ x,        // (B,T,4)
    const float* __restrict__ state,    // (B,T,4)
    const float* __restrict__ kernel,   // (4,200)
    const float* __restrict__ rec,      // (50,200)
    const float* __restrict__ bias,     // (200,)
    const float* __restrict__ w_dv, const float* __restrict__ b_dv,
    const float* __restrict__ w_dt, const float* __restrict__ b_dt,
    const float* __restrict__ w_mj, const float* __restrict__ b_mj,
    const float* __restrict__ w_ma, const float* __restrict__ b_ma,
    const float* __restrict__ w_mi, const float* __restrict__ b_mi,
    float* __restrict__ out)            // act_seq (B*T) then idm (B*5)
{
    const int b = blockIdx.x;
    const int l = threadIdx.x;
    const int cl = (l < U) ? l : (U - 1);   // clamped column lane

    __shared__ __align__(16) _Float16 h16[64];  // dword k = packed h pair k
    __shared__ float idm[8];

    // ---- stage rec into 100 AGPRs (packed f16 pairs) ----
    uint32_t wa[100];
    #pragma unroll
    for (int g = 0; g < 4; ++g) {
        #pragma unroll
        for (int j = 0; j < 25; ++j) {
            float r0 = rec[(2 * j) * 200 + g * U + cl];
            float r1 = rec[(2 * j + 1) * 200 + g * U + cl];
            half2v p; p.x = (_Float16)r0; p.y = (_Float16)r1;
            uint32_t packed = __builtin_bit_cast(uint32_t, p);
            AWRITE(wa[g * 25 + j], packed);
        }
    }
    // ---- kernel (16) + bias (4) into AGPRs ----
    float ka[16];
    #pragma unroll
    for (int g = 0; g < 4; ++g) {
        #pragma unroll
        for (int f = 0; f < 4; ++f) {
            float kv = kernel[f * 200 + g * U + cl];
            AWRITE(ka[g * 4 + f], kv);
        }
    }
    float ba[4];
    #pragma unroll
    for (int g = 0; g < 4; ++g) {
        float bv = bias[g * U + cl];
        AWRITE(ba[g], bv);
    }

    h16[l] = (_Float16)0.0f;
    float c = 0.0f;

    const float4* __restrict__ xb4 = (const float4*)(x + (size_t)b * TT * 4);
    const uint4* __restrict__ hq = (const uint4*)h16;
    const uint32_t* __restrict__ hd = (const uint32_t*)h16;

    float4 x4 = xb4[0];

    // pipelined h fragment (zeros at t=0)
    uint32_t hvu[25];
    #pragma unroll
    for (int q = 0; q < 6; ++q) {
        uint4 v = hq[q];
        hvu[4 * q + 0] = v.x; hvu[4 * q + 1] = v.y;
        hvu[4 * q + 2] = v.z; hvu[4 * q + 3] = v.w;
    }
    hvu[24] = hd[24];

    for (int t = 0; t < TT; ++t) {
        float4 x4n = xb4[(t + 1 < TT) ? (t + 1) : t];  // prefetch, used next iter

        // x-part: operands pulled from AGPRs (independent of h)
        float zx[4];
        #pragma unroll
        for (int g = 0; g < 4; ++g) {
            float k0, k1, k2, k3, b0;
            AREAD(k0, ka[g * 4 + 0]);
            AREAD(k1, ka[g * 4 + 1]);
            AREAD(k2, ka[g * 4 + 2]);
            AREAD(k3, ka[g * 4 + 3]);
            AREAD(b0, ba[g]);
            zx[g] = fmaf(x4.x, k0, fmaf(x4.y, k1, fmaf(x4.z, k2, fmaf(x4.w, k3, b0))));
        }

        // recurrent GEMV: 100 accvgpr_read + 100 v_dot2_f32_f16, 8 acc chains
        float acc[8] = {0.f, 0.f, 0.f, 0.f, 0.f, 0.f, 0.f, 0.f};
        #pragma unroll
        for (int j = 0; j < 25; ++j) {
            const int s = (j & 1) * 4;
            uint32_t w0, w1, w2, w3;
            AREAD(w0, wa[0 * 25 + j]);
            AREAD(w1, wa[1 * 25 + j]);
            AREAD(w2, wa[2 * 25 + j]);
            AREAD(w3, wa[3 * 25 + j]);
            dot2_asm(acc[s + 0], hvu[j], w0);
            dot2_asm(acc[s + 1], hvu[j], w1);
            dot2_asm(acc[s + 2], hvu[j], w2);
            dot2_asm(acc[s + 3], hvu[j], w3);
        }

        float zi = zx[0] + acc[0] + acc[4];
        float zf = zx[1] + acc[1] + acc[5];
        float zg = zx[2] + acc[2] + acc[6];
        float zo = zx[3] + acc[3] + acc[7];

        float ig = sigmoid_fast(zi);
        float fg = sigmoid_fast(zf);
        float gg = tanh_fast(zg);
        float og = sigmoid_fast(zo);
        c = fmaf(fg, c, ig * gg);
        float hnew = og * tanh_fast(c);
        if (l < U) h16[l] = (_Float16)hnew;

        // re-read h immediately; latency hides under next step's zx/AREADs
        #pragma unroll
        for (int q = 0; q < 6; ++q) {
            uint4 v = hq[q];
            hvu[4 * q + 0] = v.x; hvu[4 * q + 1] = v.y;
            hvu[4 * q + 2] = v.z; hvu[4 * q + 3] = v.w;
        }
        hvu[24] = hd[24];

        x4 = x4n;
        // no barrier: single wave, in-order LDS pipeline + compiler lgkmcnt
    }

    // ---- 5 output heads (lanes 0..4) ----
    if (l < 5) {
        const float* w  = (l == 0) ? w_dv : (l == 1) ? w_dt :
                          (l == 2) ? w_mj : (l == 3) ? w_ma : w_mi;
        const float* bb = (l == 0) ? b_dv : (l == 1) ? b_dt :
                          (l == 2) ? b_mj : (l == 3) ? b_ma : b_mi;
        float s = bb[0];
        #pragma unroll
        for (int j = 0; j < U; ++j) s = fmaf((float)h16[j], w[j], s);
        float v;
        if (l == 0)      v = param_act(s, 15.0f, 35.0f);
        else if (l == 1) v = param_act(s, 0.5f, 3.0f);
        else if (l == 2) v = fmaxf(s, 0.0f);
        else if (l == 3) v = param_act(s, 0.5f, 3.0f);
        else             v = param_act(s, 0.5f, 4.0f);
        idm[l] = v;
        out[BB * TT + b * 5 + l] = v;
    }

    // ---- IDM physics over T ----
    const float desired_v    = idm[0];
    const float desired_tgap = idm[1];
    const float min_jamx     = idm[2];
    const float max_act      = idm[3];
    const float min_act      = idm[4];
    const float inv_tsab = 1.0f / (2.0f * sqrtf(max_act * min_act));
    const float inv_dv   = 1.0f / desired_v;

    const float4* __restrict__ sb4 = (const float4*)(state + (size_t)b * TT * 4);
    for (int t = l; t < TT; t += 64) {
        float4 s4 = sb4[t];
        float vel = s4.x;
        float dv  = s4.z;
        float dx  = s4.w;
        float dgap = fmaf(desired_tgap, vel, fmaf(vel * dv, inv_tsab, min_jamx));
        float r1 = vel * inv_dv;
        r1 = r1 * r1;
        r1 = r1 * r1;            // ^4
        float r2 = dgap / dx;
        r2 = r2 * r2;            // ^2
        out[b * TT + t] = max_act * (1.0f - (r1 + r2));
    }
}

extern "C" void kernel_launch(void* const* d_in, const int* in_sizes, int n_in,
                              void* d_out, int out_size, void* d_ws, size_t ws_size,
                              hipStream_t stream) {
    const float* x      = (const float*)d_in[0];
    const float* state  = (const float*)d_in[1];
    const float* kern   = (const float*)d_in[2];
    const float* rec    = (const float*)d_in[3];
    const float* bias   = (const float*)d_in[4];
    const float* w_dv   = (const float*)d_in[5];
    const float* b_dv   = (const float*)d_in[6];
    const float* w_dt   = (const float*)d_in[7];
    const float* b_dt   = (const float*)d_in[8];
    const float* w_mj   = (const float*)d_in[9];
    const float* b_mj   = (const float*)d_in[10];
    const float* w_ma   = (const float*)d_in[11];
    const float* b_ma   = (const float*)d_in[12];
    const float* w_mi   = (const float*)d_in[13];
    const float* b_mi   = (const float*)d_in[14];
    float* out = (float*)d_out;

    encoder_kernel<<<BB, 64, 0, stream>>>(
        x, state, kern, rec, bias,
        w_dv, b_dv, w_dt, b_dt, w_mj, b_mj, w_ma, b_ma, w_mi, b_mi,
        out);
}